// Round 7
// baseline (364.631 us; speedup 1.0000x reference)
//
#include <hip/hip_runtime.h>

// Problem constants (from reference)
#define N_U 100000
#define N_V 100000
#define OO 64
#define RR 5
#define EE 500000
#define TOT_E (RR * EE)   // 2,500,000 edges per direction (TOT_E % 8 == 0)
#define NB 782            // buckets of 128 dst nodes (781*128=99968, last=32)
#define CAP 4096          // payload window stride per bucket (entries)
#define CAPU 3584         // max entries per bucket (mean 3197, +6.8 sigma)
#define NPB 32            // nodes per sort_agg block (bucket quarter)
#define CAPS 1280         // per-quarter LDS capacity (mean 800+96 pad, >10 sigma)

typedef short bf16x8 __attribute__((ext_vector_type(8)));
typedef float f32x4 __attribute__((ext_vector_type(4)));

__device__ __forceinline__ float bf2f(unsigned short u) {
  union { unsigned int i; float f; } x;
  x.i = ((unsigned int)u) << 16;
  return x.f;
}
__device__ __forceinline__ unsigned short f2bf(float f) {
  union { float f; unsigned int i; } x;
  x.f = f;
  unsigned int lsb = (x.i >> 16) & 1u;
  unsigned int r = x.i + 0x7fffu + lsb;   // round-to-nearest-even
  return (unsigned short)(r >> 16);
}

// ---------------------------------------------------------------------------
// Cumsum the per-relation fp32 weights, write bf16 in MFMA B-fragment order.
// bfrag layout: [side(2)=u,v][r(5)][4096]
// ---------------------------------------------------------------------------
__global__ void prep_weights(const float* __restrict__ wu,
                             const float* __restrict__ wv,
                             unsigned short* __restrict__ bfrag) {
  int side = blockIdx.x;
  const float* w = side ? wv : wu;
  for (int idx = threadIdx.x; idx < 4096; idx += 256) {
    int d = idx >> 6, o = idx & 63;
    int c = o >> 4, n = o & 15;
    int sk = d >> 5, q = (d >> 3) & 3, jj = d & 7;
    int f = c * 2 + sk;
    int lane = q * 16 + n;
    int pos = (f * 64 + lane) * 8 + jj;
    float acc = 0.f;
    for (int r = 0; r < RR; ++r) {
      acc += w[r * 4096 + idx];
      bfrag[(side * RR + r) * 4096 + pos] = f2bf(acc);
    }
  }
}

// ---------------------------------------------------------------------------
// All-5-relations GEMM: tmp5[r] = X @ Wcum[r], bf16, lane-permuted row layout
// tmp_r[row*64 + m*4 + c] = D[row][c*16+m] (8 B/lane stores).
// ---------------------------------------------------------------------------
__global__ __launch_bounds__(256) void gemm5_kernel(
    const float* __restrict__ X,
    const unsigned short* __restrict__ bfrag_side,  // [r(5)][4096]
    unsigned short* __restrict__ tmp5) {            // [r(5)][100000][64]
  __shared__ unsigned short smem[RR * 4096];
  for (int idx = threadIdx.x; idx < RR * 4096; idx += 256)
    smem[idx] = bfrag_side[idx];
  __syncthreads();

  int lane = threadIdx.x & 63;
  int wave = threadIdx.x >> 6;
  int q = lane >> 4, m = lane & 15;
  int t = blockIdx.x * 4 + wave;
  if (t >= N_U / 16) return;
  int r0 = t * 16;

  const float* xr = X + (size_t)(r0 + m) * 64;
  float4 p0 = *(const float4*)(xr + q * 8);
  float4 p1 = *(const float4*)(xr + q * 8 + 4);
  float4 p2 = *(const float4*)(xr + 32 + q * 8);
  float4 p3 = *(const float4*)(xr + 32 + q * 8 + 4);
  bf16x8 a0, a1;
  a0[0] = (short)f2bf(p0.x); a0[1] = (short)f2bf(p0.y);
  a0[2] = (short)f2bf(p0.z); a0[3] = (short)f2bf(p0.w);
  a0[4] = (short)f2bf(p1.x); a0[5] = (short)f2bf(p1.y);
  a0[6] = (short)f2bf(p1.z); a0[7] = (short)f2bf(p1.w);
  a1[0] = (short)f2bf(p2.x); a1[1] = (short)f2bf(p2.y);
  a1[2] = (short)f2bf(p2.z); a1[3] = (short)f2bf(p2.w);
  a1[4] = (short)f2bf(p3.x); a1[5] = (short)f2bf(p3.y);
  a1[6] = (short)f2bf(p3.z); a1[7] = (short)f2bf(p3.w);

  for (int r = 0; r < RR; ++r) {
    f32x4 acc[4];
#pragma unroll
    for (int c = 0; c < 4; ++c) {
      bf16x8 b0 = *(const bf16x8*)(smem + r * 4096 + ((c * 2 + 0) * 64 + lane) * 8);
      bf16x8 b1 = *(const bf16x8*)(smem + r * 4096 + ((c * 2 + 1) * 64 + lane) * 8);
      f32x4 a = {0.f, 0.f, 0.f, 0.f};
      a = __builtin_amdgcn_mfma_f32_16x16x32_bf16(a0, b0, a, 0, 0, 0);
      a = __builtin_amdgcn_mfma_f32_16x16x32_bf16(a1, b1, a, 0, 0, 0);
      acc[c] = a;
    }
    unsigned short* trow = tmp5 + (size_t)r * N_U * 64;
#pragma unroll
    for (int i = 0; i < 4; ++i) {
      ushort4 o;
      o.x = f2bf(acc[0][i]); o.y = f2bf(acc[1][i]);
      o.z = f2bf(acc[2][i]); o.w = f2bf(acc[3][i]);
      *(ushort4*)(trow + (size_t)(r0 + q * 4 + i) * 64 + m * 4) = o;
    }
  }
}

// ---------------------------------------------------------------------------
// gcursor[b] = b*CAP (window base). Re-run per side (ws is re-poisoned).
// ---------------------------------------------------------------------------
__global__ void init_cursor(unsigned* __restrict__ g) {
  int i = blockIdx.x * 256 + threadIdx.x;
  if (i < NB) g[i] = (unsigned)i * CAP;
}

// ---------------------------------------------------------------------------
// Multi-split scatter, LDS-staged coalesced form. Per block (8192 edges,
// 1024 threads): histogram per bucket -> Hillis-Steele scan (1024-wide) ->
// reserve one contiguous global run per (block,bucket) with ONE atomic ->
// place entries bucket-sorted into LDS (skey/sval/sbid) -> linear flush:
// consecutive threads write consecutive sorted entries, so each run is one
// contiguous burst. key = dstLow(7b)<<19 | (r*N_U + src)(19b).
// LDS: 32768+16384+16384+3128+4096+3128 = 75.9 KB -> 2 blocks/CU.
// ---------------------------------------------------------------------------
__global__ __launch_bounds__(1024) void bucket_scatter(
    const int* __restrict__ dst, const int* __restrict__ src,
    const float* __restrict__ val, unsigned* __restrict__ gcursor,
    unsigned* __restrict__ keyP, unsigned short* __restrict__ valP) {
  __shared__ unsigned skey[8192];
  __shared__ unsigned short sval[8192];
  __shared__ unsigned short sbid[8192];
  __shared__ unsigned cnt[NB];    // counts -> local exclusive starts
  __shared__ unsigned sc[1024];   // scan buffer -> local cursors
  __shared__ unsigned gbase[NB];
  int tid = threadIdx.x;
  for (int i = tid; i < NB; i += 1024) cnt[i] = 0u;
  __syncthreads();
  int base = blockIdx.x * 8192;
  int t8 = base + tid * 8;
  bool full = (t8 < TOT_E);
  if (full) {
    int4 d0 = *(const int4*)(dst + t8);
    int4 d1 = *(const int4*)(dst + t8 + 4);
    atomicAdd(&cnt[d0.x >> 7], 1u);
    atomicAdd(&cnt[d0.y >> 7], 1u);
    atomicAdd(&cnt[d0.z >> 7], 1u);
    atomicAdd(&cnt[d0.w >> 7], 1u);
    atomicAdd(&cnt[d1.x >> 7], 1u);
    atomicAdd(&cnt[d1.y >> 7], 1u);
    atomicAdd(&cnt[d1.z >> 7], 1u);
    atomicAdd(&cnt[d1.w >> 7], 1u);
  }
  __syncthreads();
  // inclusive scan of cnt (NB entries, zero-padded to 1024)
  sc[tid] = (tid < NB) ? cnt[tid] : 0u;
  __syncthreads();
  for (int off = 1; off < 1024; off <<= 1) {
    unsigned a = sc[tid];
    unsigned b = (tid >= off) ? sc[tid - off] : 0u;
    __syncthreads();
    sc[tid] = a + b;
    __syncthreads();
  }
  // reserve global runs; convert cnt to local exclusive starts
  for (int b = tid; b < NB; b += 1024) {
    unsigned c = cnt[b];
    gbase[b] = c ? atomicAdd(&gcursor[b], c) : 0u;
    cnt[b] = sc[b] - c;
  }
  __syncthreads();
  unsigned total = sc[NB - 1];
  __syncthreads();
  for (int b = tid; b < NB; b += 1024) sc[b] = cnt[b];   // local cursors
  __syncthreads();
  if (full) {
    int4 d0 = *(const int4*)(dst + t8);
    int4 d1 = *(const int4*)(dst + t8 + 4);
    int4 s0 = *(const int4*)(src + t8);
    int4 s1 = *(const int4*)(src + t8 + 4);
    float4 v0 = *(const float4*)(val + t8);
    float4 v1 = *(const float4*)(val + t8 + 4);
    unsigned rb = (unsigned)(t8 / EE) * N_U;
#define PUT(dd, ss, vv)                                                     \
    {                                                                       \
      int bb = (dd) >> 7;                                                   \
      unsigned pos = atomicAdd(&sc[bb], 1u);                                \
      skey[pos] = (((unsigned)((dd) & 127)) << 19) | (rb + (unsigned)(ss)); \
      sval[pos] = f2bf(vv);                                                 \
      sbid[pos] = (unsigned short)bb;                                       \
    }
    PUT(d0.x, s0.x, v0.x)
    PUT(d0.y, s0.y, v0.y)
    PUT(d0.z, s0.z, v0.z)
    PUT(d0.w, s0.w, v0.w)
    PUT(d1.x, s1.x, v1.x)
    PUT(d1.y, s1.y, v1.y)
    PUT(d1.z, s1.z, v1.z)
    PUT(d1.w, s1.w, v1.w)
#undef PUT
  }
  __syncthreads();
  // coalesced flush: consecutive i -> consecutive addr within each run
  for (int i = tid; i < (int)total; i += 1024) {
    unsigned b = sbid[i];
    unsigned addr = gbase[b] + ((unsigned)i - cnt[b]);
    keyP[addr] = skey[i];
    valP[addr] = sval[i];
  }
}

// ---------------------------------------------------------------------------
// MERGED sort + aggregate, bucket-QUARTER form: 4 blocks per bucket, each
// owns 32 nodes (quarter = key bits 24-25 = dstLow>>5). Grid 3128 blocks
// (~12/CU) fills the wave cap and averages bucket-size variance (R6 fix for
// 54% occupancy at 782 blocks). Both passes re-read the bucket's keys
// (coalesced, L2/LLC-hot) and filter by quarter. Counting sort into
// okey/oval (node ranges padded to mult of 4, pads zeroed). Agg: 8 waves,
// 4 nodes/wave; 16-lane group g16 reads its group's key/val via broadcast
// ds_read, gathers the 128-B tmp5 row (ushort4/lane), register-FMA;
// 2-round shfl_xor(16,32) reduce; lane L writes output column L.
// LDS: 5120+2560+128+132+128 = 8.1 KB -> wave-capped 4 blocks/CU.
// ---------------------------------------------------------------------------
__global__ __launch_bounds__(512, 8) void bucket_sort_agg(
    const unsigned* __restrict__ keyP, const unsigned short* __restrict__ valP,
    const unsigned* __restrict__ gcursor,
    const unsigned short* __restrict__ tmp5,
    const float* __restrict__ bias, float* __restrict__ out) {
  __shared__ unsigned okey[CAPS];
  __shared__ unsigned short oval[CAPS];
  __shared__ unsigned hist[NPB];
  __shared__ unsigned starts[NPB + 1];
  __shared__ unsigned cur[NPB];
  int bq = blockIdx.x;
  int b = bq >> 2;
  unsigned quarter = (unsigned)(bq & 3);
  unsigned base = (unsigned)b * CAP;
  int cnt = (int)(gcursor[b] - base);
  if (cnt > CAPU) cnt = CAPU;   // ~7-sigma, statistically impossible
  for (int i = threadIdx.x; i < NPB; i += 512) hist[i] = 0u;
  __syncthreads();
  for (int i = threadIdx.x; i < cnt; i += 512) {
    unsigned k = keyP[base + i];
    if (((k >> 24) & 3u) == quarter) atomicAdd(&hist[(k >> 19) & 31u], 1u);
  }
  __syncthreads();
  if (threadIdx.x == 0) {
    unsigned acc = 0u;
    for (int l = 0; l < NPB; ++l) {
      starts[l] = acc < CAPS ? acc : CAPS;
      acc += (hist[l] + 3u) & ~3u;   // pad each node to multiple of 4
    }
    starts[NPB] = acc < CAPS ? acc : CAPS;
  }
  __syncthreads();
  unsigned tot = starts[NPB];
  for (int i = threadIdx.x; i < (int)tot; i += 512) { okey[i] = 0u; oval[i] = 0; }
  for (int l = threadIdx.x; l < NPB; l += 512) cur[l] = starts[l];
  __syncthreads();
  for (int i = threadIdx.x; i < cnt; i += 512) {   // L2-hot re-read
    unsigned k = keyP[base + i];
    if (((k >> 24) & 3u) == quarter) {
      unsigned pos = atomicAdd(&cur[(k >> 19) & 31u], 1u);
      if (pos < CAPS) {
        okey[pos] = k & 0x7FFFFu;
        oval[pos] = valP[base + i];
      }
    }
  }
  __syncthreads();

  // ---- aggregation from LDS ----
  int lane = threadIdx.x & 63;
  int wave = threadIdx.x >> 6;
  int g16 = lane >> 4;                      // entry subgroup 0..3
  int m = lane & 15;                        // column-slot group
  int nb0 = b * 128 + (int)quarter * NPB;
  int nodes = N_U - nb0;
  if (nodes > NPB) nodes = NPB;
  const unsigned short* tp = tmp5 + (m << 2);
  float bl = bias[lane];
  for (int l = wave; l < nodes; l += 8) {
    unsigned s = starts[l];
    unsigned e = starts[l + 1];
    float a0 = 0.f, a1 = 0.f, a2 = 0.f, a3 = 0.f;
    unsigned k = s;
    for (; k + 8 <= e; k += 8) {            // 2 gathers in flight
      unsigned key0 = okey[k + g16];
      unsigned key1 = okey[k + 4 + g16];
      float v0 = bf2f(oval[k + g16]);
      float v1 = bf2f(oval[k + 4 + g16]);
      ushort4 t0 = *(const ushort4*)(tp + (size_t)key0 * 64);
      ushort4 t1 = *(const ushort4*)(tp + (size_t)key1 * 64);
      a0 += v0 * bf2f(t0.x);
      a1 += v0 * bf2f(t0.y);
      a2 += v0 * bf2f(t0.z);
      a3 += v0 * bf2f(t0.w);
      a0 += v1 * bf2f(t1.x);
      a1 += v1 * bf2f(t1.y);
      a2 += v1 * bf2f(t1.z);
      a3 += v1 * bf2f(t1.w);
    }
    if (k < e) {                            // padded remainder: one group
      unsigned key0 = okey[k + g16];
      float v0 = bf2f(oval[k + g16]);
      ushort4 t0 = *(const ushort4*)(tp + (size_t)key0 * 64);
      a0 += v0 * bf2f(t0.x);
      a1 += v0 * bf2f(t0.y);
      a2 += v0 * bf2f(t0.z);
      a3 += v0 * bf2f(t0.w);
    }
    a0 += __shfl_xor(a0, 16); a0 += __shfl_xor(a0, 32);
    a1 += __shfl_xor(a1, 16); a1 += __shfl_xor(a1, 32);
    a2 += __shfl_xor(a2, 16); a2 += __shfl_xor(a2, 32);
    a3 += __shfl_xor(a3, 16); a3 += __shfl_xor(a3, 32);
    float r = (g16 & 2) ? ((g16 & 1) ? a3 : a2) : ((g16 & 1) ? a1 : a0);
    out[(size_t)(nb0 + l) * 64 + lane] = fmaxf(r + bl, 0.f);
  }
}

// ===========================================================================
// FALLBACK PATH (proven R4 atomic-scatter version, used if ws is small)
// ===========================================================================
__global__ __launch_bounds__(256) void gemm_kernel(
    const float* __restrict__ X, const unsigned short* __restrict__ bfrag,
    unsigned short* __restrict__ tmp) {
  int lane = threadIdx.x & 63;
  int wave = threadIdx.x >> 6;
  int q = lane >> 4, m = lane & 15;
  bf16x8 bf[8];
#pragma unroll
  for (int f = 0; f < 8; ++f)
    bf[f] = *(const bf16x8*)(bfrag + (f * 64 + lane) * 8);
  int t = blockIdx.x * 4 + wave;
  if (t >= N_U / 16) return;
  int r0 = t * 16;
  const float* xr = X + (size_t)(r0 + m) * 64;
  float4 p0 = *(const float4*)(xr + q * 8);
  float4 p1 = *(const float4*)(xr + q * 8 + 4);
  float4 p2 = *(const float4*)(xr + 32 + q * 8);
  float4 p3 = *(const float4*)(xr + 32 + q * 8 + 4);
  bf16x8 a0, a1;
  a0[0] = (short)f2bf(p0.x); a0[1] = (short)f2bf(p0.y);
  a0[2] = (short)f2bf(p0.z); a0[3] = (short)f2bf(p0.w);
  a0[4] = (short)f2bf(p1.x); a0[5] = (short)f2bf(p1.y);
  a0[6] = (short)f2bf(p1.z); a0[7] = (short)f2bf(p1.w);
  a1[0] = (short)f2bf(p2.x); a1[1] = (short)f2bf(p2.y);
  a1[2] = (short)f2bf(p2.z); a1[3] = (short)f2bf(p2.w);
  a1[4] = (short)f2bf(p3.x); a1[5] = (short)f2bf(p3.y);
  a1[6] = (short)f2bf(p3.z); a1[7] = (short)f2bf(p3.w);
#pragma unroll
  for (int c = 0; c < 4; ++c) {
    f32x4 acc = {0.f, 0.f, 0.f, 0.f};
    acc = __builtin_amdgcn_mfma_f32_16x16x32_bf16(a0, bf[c * 2 + 0], acc, 0, 0, 0);
    acc = __builtin_amdgcn_mfma_f32_16x16x32_bf16(a1, bf[c * 2 + 1], acc, 0, 0, 0);
#pragma unroll
    for (int i = 0; i < 4; ++i)
      tmp[(size_t)(r0 + q * 4 + i) * 64 + c * 16 + m] = f2bf(acc[i]);
  }
}

__global__ __launch_bounds__(256) void scatter_kernel(
    const unsigned short* __restrict__ tmp, const float* __restrict__ edge_val,
    const int* __restrict__ dst_idx, const int* __restrict__ src_idx,
    float* __restrict__ z, int base, int cnt) {
  int e = blockIdx.x * 4 + (threadIdx.x >> 6);
  int j = threadIdx.x & 63;
  int d = dst_idx[e] - base;
  if ((unsigned)d >= (unsigned)cnt) return;
  int s = src_idx[e];
  float w = edge_val[e];
  atomicAdd(&z[(size_t)d * 64 + j], w * bf2f(tmp[(size_t)s * 64 + j]));
}

__global__ __launch_bounds__(256) void finalize_kernel(
    const float* __restrict__ z, const float* __restrict__ bias,
    float* __restrict__ out) {
  size_t i4 = ((size_t)blockIdx.x * 256 + threadIdx.x) * 4;
  float4 zz = *(const float4*)(z + i4);
  const float4 bb = *(const float4*)(bias + (i4 & 63));
  float4 o;
  o.x = fmaxf(zz.x + bb.x, 0.f);
  o.y = fmaxf(zz.y + bb.y, 0.f);
  o.z = fmaxf(zz.z + bb.z, 0.f);
  o.w = fmaxf(zz.w + bb.w, 0.f);
  *(float4*)(out + i4) = o;
}

extern "C" void kernel_launch(void* const* d_in, const int* in_sizes, int n_in,
                              void* d_out, int out_size, void* d_ws, size_t ws_size,
                              hipStream_t stream) {
  const float* x_u      = (const float*)d_in[0];
  const float* x_v      = (const float*)d_in[1];
  const float* w_u      = (const float*)d_in[2];
  const float* w_v      = (const float*)d_in[3];
  const float* bias_u   = (const float*)d_in[4];
  const float* bias_v   = (const float*)d_in[5];
  const float* edge_val = (const float*)d_in[6];
  const int*   edge_u   = (const int*)d_in[7];
  const int*   edge_v   = (const int*)d_in[8];
  float* out = (float*)d_out;
  char* ws = (char*)d_ws;

  // Fast-path ws layout (83.8 MB <= R5/R8-proven 84.9 MB):
  //   bfrag    @ 0           131,072
  //   tmp5     @ 131,072     64,000,000                 -> 64,131,072
  //   gcursor  @ 64,131,072  4,096                      -> 64,135,168
  //   (unused) @ 64,135,168  409,600                    -> 64,544,768
  //   keyP     @ 64,544,768  782*4096*4 = 12,812,288    -> 77,357,056
  //   valP     @ 77,357,056  782*4096*2 =  6,406,144    -> 83,763,200
  const size_t FAST_NEED = 83763200;

  unsigned short* bfrag = (unsigned short*)ws;
  prep_weights<<<2, 256, 0, stream>>>(w_u, w_v, bfrag);

  if (ws_size >= FAST_NEED) {
    unsigned short* tmp5      = (unsigned short*)(ws + 131072);
    unsigned*       gcursor   = (unsigned*)(ws + 64131072);
    unsigned*       keyP      = (unsigned*)(ws + 64544768);
    unsigned short* valP      = (unsigned short*)(ws + 77357056);

    const int edge_grid = (TOT_E + 8191) / 8192;  // 306
    const int gemm_grid = (N_U / 16 + 3) / 4;     // 1563

    for (int side = 0; side < 2; ++side) {
      // side 0: out_u <- tmp of x_v @ Wcum_v, dst=edge_u, src=edge_v
      // side 1: out_v <- tmp of x_u @ Wcum_u, dst=edge_v, src=edge_u
      const float* X = side ? x_u : x_v;
      const unsigned short* frag0 = bfrag + (side ? 0 : RR * 4096);
      const int* dst = side ? edge_v : edge_u;
      const int* src = side ? edge_u : edge_v;
      const float* bias = side ? bias_v : bias_u;
      float* out_side = out + (size_t)side * N_U * OO;

      init_cursor<<<4, 256, 0, stream>>>(gcursor);
      bucket_scatter<<<edge_grid, 1024, 0, stream>>>(dst, src, edge_val, gcursor,
                                                     keyP, valP);
      gemm5_kernel<<<gemm_grid, 256, 0, stream>>>(X, frag0, tmp5);
      bucket_sort_agg<<<NB * 4, 512, 0, stream>>>(keyP, valP, gcursor, tmp5, bias,
                                                  out_side);
    }
    return;
  }

  // ---------------- Fallback: proven R4 path ----------------
  unsigned short* tmp = (unsigned short*)(ws + 131072);
  float*          z   = (float*)(ws + 131072 + 12800000);
  const size_t fixed = 131072 + 12800000;
  size_t zbytes = ws_size > fixed ? ws_size - fixed : 0;
  long chunk = (long)(zbytes / (OO * 4));
  chunk -= chunk % 16;
  if (chunk < 16) chunk = 16;
  if (chunk > N_U) chunk = N_U;

  const int gemm_grid = (N_U / 16 + 3) / 4;
  const int scat_grid = EE / 4;

  for (int side = 0; side < 2; ++side) {
    const float* X = side ? x_u : x_v;
    const unsigned short* frag0 = bfrag + (side ? 0 : RR * 4096);
    const int* dst = side ? edge_v : edge_u;
    const int* src = side ? edge_u : edge_v;
    const float* bias = side ? bias_v : bias_u;
    float* out_side = out + (size_t)side * N_U * OO;

    for (long base = 0; base < N_U; base += chunk) {
      long cnt = N_U - base < chunk ? N_U - base : chunk;
      hipMemsetAsync(z, 0, (size_t)cnt * OO * 4, stream);
      for (int r = 0; r < RR; ++r) {
        gemm_kernel<<<gemm_grid, 256, 0, stream>>>(X, frag0 + r * 4096, tmp);
        scatter_kernel<<<scat_grid, 256, 0, stream>>>(
            tmp, edge_val + (size_t)r * EE, dst + (size_t)r * EE,
            src + (size_t)r * EE, z, (int)base, (int)cnt);
      }
      finalize_kernel<<<(int)(cnt / 16), 256, 0, stream>>>(
          z, bias, out_side + base * OO);
    }
  }
}

// Round 9
// 337.919 us; speedup vs baseline: 1.0790x; 1.0790x over previous
//
#include <hip/hip_runtime.h>

// Problem constants (from reference)
#define N_U 100000
#define N_V 100000
#define OO 64
#define RR 5
#define EE 500000
#define TOT_E (RR * EE)   // 2,500,000 edges per direction (TOT_E % 8 == 0)
#define NB 782            // buckets of 128 dst nodes (781*128=99968, last=32)
#define CAP 4096          // payload window stride per bucket (entries)
#define CAPU 3584         // max entries per bucket (mean 3197, +6.8 sigma)

typedef short bf16x8 __attribute__((ext_vector_type(8)));
typedef float f32x4 __attribute__((ext_vector_type(4)));

__device__ __forceinline__ float bf2f(unsigned short u) {
  union { unsigned int i; float f; } x;
  x.i = ((unsigned int)u) << 16;
  return x.f;
}
__device__ __forceinline__ unsigned short f2bf(float f) {
  union { float f; unsigned int i; } x;
  x.f = f;
  unsigned int lsb = (x.i >> 16) & 1u;
  unsigned int r = x.i + 0x7fffu + lsb;   // round-to-nearest-even
  return (unsigned short)(r >> 16);
}

// ---------------------------------------------------------------------------
// Cumsum the per-relation fp32 weights, write bf16 in MFMA B-fragment order.
// bfrag layout: [side(2)=u,v][r(5)][4096]
// ---------------------------------------------------------------------------
__global__ void prep_weights(const float* __restrict__ wu,
                             const float* __restrict__ wv,
                             unsigned short* __restrict__ bfrag) {
  int side = blockIdx.x;
  const float* w = side ? wv : wu;
  for (int idx = threadIdx.x; idx < 4096; idx += 256) {
    int d = idx >> 6, o = idx & 63;
    int c = o >> 4, n = o & 15;
    int sk = d >> 5, q = (d >> 3) & 3, jj = d & 7;
    int f = c * 2 + sk;
    int lane = q * 16 + n;
    int pos = (f * 64 + lane) * 8 + jj;
    float acc = 0.f;
    for (int r = 0; r < RR; ++r) {
      acc += w[r * 4096 + idx];
      bfrag[(side * RR + r) * 4096 + pos] = f2bf(acc);
    }
  }
}

// ---------------------------------------------------------------------------
// All-5-relations GEMM: tmp5[r] = X @ Wcum[r], bf16, lane-permuted row layout
// tmp_r[row*64 + m*4 + c] = D[row][c*16+m] (8 B/lane stores).
// ---------------------------------------------------------------------------
__global__ __launch_bounds__(256) void gemm5_kernel(
    const float* __restrict__ X,
    const unsigned short* __restrict__ bfrag_side,  // [r(5)][4096]
    unsigned short* __restrict__ tmp5) {            // [r(5)][100000][64]
  __shared__ unsigned short smem[RR * 4096];
  for (int idx = threadIdx.x; idx < RR * 4096; idx += 256)
    smem[idx] = bfrag_side[idx];
  __syncthreads();

  int lane = threadIdx.x & 63;
  int wave = threadIdx.x >> 6;
  int q = lane >> 4, m = lane & 15;
  int t = blockIdx.x * 4 + wave;
  if (t >= N_U / 16) return;
  int r0 = t * 16;

  const float* xr = X + (size_t)(r0 + m) * 64;
  float4 p0 = *(const float4*)(xr + q * 8);
  float4 p1 = *(const float4*)(xr + q * 8 + 4);
  float4 p2 = *(const float4*)(xr + 32 + q * 8);
  float4 p3 = *(const float4*)(xr + 32 + q * 8 + 4);
  bf16x8 a0, a1;
  a0[0] = (short)f2bf(p0.x); a0[1] = (short)f2bf(p0.y);
  a0[2] = (short)f2bf(p0.z); a0[3] = (short)f2bf(p0.w);
  a0[4] = (short)f2bf(p1.x); a0[5] = (short)f2bf(p1.y);
  a0[6] = (short)f2bf(p1.z); a0[7] = (short)f2bf(p1.w);
  a1[0] = (short)f2bf(p2.x); a1[1] = (short)f2bf(p2.y);
  a1[2] = (short)f2bf(p2.z); a1[3] = (short)f2bf(p2.w);
  a1[4] = (short)f2bf(p3.x); a1[5] = (short)f2bf(p3.y);
  a1[6] = (short)f2bf(p3.z); a1[7] = (short)f2bf(p3.w);

  for (int r = 0; r < RR; ++r) {
    f32x4 acc[4];
#pragma unroll
    for (int c = 0; c < 4; ++c) {
      bf16x8 b0 = *(const bf16x8*)(smem + r * 4096 + ((c * 2 + 0) * 64 + lane) * 8);
      bf16x8 b1 = *(const bf16x8*)(smem + r * 4096 + ((c * 2 + 1) * 64 + lane) * 8);
      f32x4 a = {0.f, 0.f, 0.f, 0.f};
      a = __builtin_amdgcn_mfma_f32_16x16x32_bf16(a0, b0, a, 0, 0, 0);
      a = __builtin_amdgcn_mfma_f32_16x16x32_bf16(a1, b1, a, 0, 0, 0);
      acc[c] = a;
    }
    unsigned short* trow = tmp5 + (size_t)r * N_U * 64;
#pragma unroll
    for (int i = 0; i < 4; ++i) {
      ushort4 o;
      o.x = f2bf(acc[0][i]); o.y = f2bf(acc[1][i]);
      o.z = f2bf(acc[2][i]); o.w = f2bf(acc[3][i]);
      *(ushort4*)(trow + (size_t)(r0 + q * 4 + i) * 64 + m * 4) = o;
    }
  }
}

// ---------------------------------------------------------------------------
// gcursor[b] = b*CAP (window base). Re-run per side (ws is re-poisoned).
// ---------------------------------------------------------------------------
__global__ void init_cursor(unsigned* __restrict__ g) {
  int i = blockIdx.x * 256 + threadIdx.x;
  if (i < NB) g[i] = (unsigned)i * CAP;
}

// ---------------------------------------------------------------------------
// Multi-split scatter, LDS-staged coalesced form. Per block (8192 edges,
// 1024 threads): histogram per bucket -> Hillis-Steele scan (1024-wide) ->
// reserve one contiguous global run per (block,bucket) with ONE atomic ->
// place entries bucket-sorted into LDS (skey/sval/sbid) -> linear flush:
// consecutive threads write consecutive sorted entries, so each run is one
// contiguous burst. key = dstLow(7b)<<19 | (r*N_U + src)(19b).
// LDS: 32768+16384+16384+3128+4096+3128 = 75.9 KB -> 2 blocks/CU.
// ---------------------------------------------------------------------------
__global__ __launch_bounds__(1024) void bucket_scatter(
    const int* __restrict__ dst, const int* __restrict__ src,
    const float* __restrict__ val, unsigned* __restrict__ gcursor,
    unsigned* __restrict__ keyP, unsigned short* __restrict__ valP) {
  __shared__ unsigned skey[8192];
  __shared__ unsigned short sval[8192];
  __shared__ unsigned short sbid[8192];
  __shared__ unsigned cnt[NB];    // counts -> local exclusive starts
  __shared__ unsigned sc[1024];   // scan buffer -> local cursors
  __shared__ unsigned gbase[NB];
  int tid = threadIdx.x;
  for (int i = tid; i < NB; i += 1024) cnt[i] = 0u;
  __syncthreads();
  int base = blockIdx.x * 8192;
  int t8 = base + tid * 8;
  bool full = (t8 < TOT_E);
  if (full) {
    int4 d0 = *(const int4*)(dst + t8);
    int4 d1 = *(const int4*)(dst + t8 + 4);
    atomicAdd(&cnt[d0.x >> 7], 1u);
    atomicAdd(&cnt[d0.y >> 7], 1u);
    atomicAdd(&cnt[d0.z >> 7], 1u);
    atomicAdd(&cnt[d0.w >> 7], 1u);
    atomicAdd(&cnt[d1.x >> 7], 1u);
    atomicAdd(&cnt[d1.y >> 7], 1u);
    atomicAdd(&cnt[d1.z >> 7], 1u);
    atomicAdd(&cnt[d1.w >> 7], 1u);
  }
  __syncthreads();
  // inclusive scan of cnt (NB entries, zero-padded to 1024)
  sc[tid] = (tid < NB) ? cnt[tid] : 0u;
  __syncthreads();
  for (int off = 1; off < 1024; off <<= 1) {
    unsigned a = sc[tid];
    unsigned b = (tid >= off) ? sc[tid - off] : 0u;
    __syncthreads();
    sc[tid] = a + b;
    __syncthreads();
  }
  // reserve global runs; convert cnt to local exclusive starts
  for (int b = tid; b < NB; b += 1024) {
    unsigned c = cnt[b];
    gbase[b] = c ? atomicAdd(&gcursor[b], c) : 0u;
    cnt[b] = sc[b] - c;
  }
  __syncthreads();
  unsigned total = sc[NB - 1];
  __syncthreads();
  for (int b = tid; b < NB; b += 1024) sc[b] = cnt[b];   // local cursors
  __syncthreads();
  if (full) {
    int4 d0 = *(const int4*)(dst + t8);
    int4 d1 = *(const int4*)(dst + t8 + 4);
    int4 s0 = *(const int4*)(src + t8);
    int4 s1 = *(const int4*)(src + t8 + 4);
    float4 v0 = *(const float4*)(val + t8);
    float4 v1 = *(const float4*)(val + t8 + 4);
    unsigned rb = (unsigned)(t8 / EE) * N_U;
#define PUT(dd, ss, vv)                                                     \
    {                                                                       \
      int bb = (dd) >> 7;                                                   \
      unsigned pos = atomicAdd(&sc[bb], 1u);                                \
      skey[pos] = (((unsigned)((dd) & 127)) << 19) | (rb + (unsigned)(ss)); \
      sval[pos] = f2bf(vv);                                                 \
      sbid[pos] = (unsigned short)bb;                                       \
    }
    PUT(d0.x, s0.x, v0.x)
    PUT(d0.y, s0.y, v0.y)
    PUT(d0.z, s0.z, v0.z)
    PUT(d0.w, s0.w, v0.w)
    PUT(d1.x, s1.x, v1.x)
    PUT(d1.y, s1.y, v1.y)
    PUT(d1.z, s1.z, v1.z)
    PUT(d1.w, s1.w, v1.w)
#undef PUT
  }
  __syncthreads();
  // coalesced flush: consecutive i -> consecutive addr within each run
  for (int i = tid; i < (int)total; i += 1024) {
    unsigned b = sbid[i];
    unsigned addr = gbase[b] + ((unsigned)i - cnt[b]);
    keyP[addr] = skey[i];
    valP[addr] = sval[i];
  }
}

// ---------------------------------------------------------------------------
// MERGED sort + aggregate (proven R5 structure; only the agg unroll is
// deepened 2->4 gathers in flight). One block per bucket, 512 threads,
// two-pass low-LDS sort: pass 1 histogram from global (coalesced); serial
// thread-0 scan (proven); pass 2 re-read (L2-hot) scatter into okey/oval
// (node ranges padded to mult of 4, pads zeroed -> contribute nothing).
// Agg: 8 waves, wave handles every-8th node; 16-lane group g16 reads its
// group's key/val via broadcast ds_read, gathers the 128-B tmp5 row
// (ushort4/lane), register-FMA; 2-round shfl_xor(16,32) reduce; lane L
// writes output column L. Inner loop x4-unrolled (16 entries -> 4 gathers
// in flight; R7 showed occupancy isn't the limiter, testing per-wave MLP).
// LDS: 16384+8192+512+516+512 = 25.6 KB -> wave-capped 4 blocks/CU.
// ---------------------------------------------------------------------------
__global__ __launch_bounds__(512, 8) void bucket_sort_agg(
    const unsigned* __restrict__ keyP, const unsigned short* __restrict__ valP,
    const unsigned* __restrict__ gcursor,
    const unsigned short* __restrict__ tmp5,
    const float* __restrict__ bias, float* __restrict__ out) {
  __shared__ unsigned okey[CAP];           // sorted+padded (max cnt+384 <= 3968)
  __shared__ unsigned short oval[CAP];
  __shared__ unsigned hist[128];
  __shared__ unsigned starts[129];
  __shared__ unsigned cur[128];
  int b = blockIdx.x;
  unsigned base = (unsigned)b * CAP;
  int cnt = (int)(gcursor[b] - base);
  if (cnt > CAPU) cnt = CAPU;   // ~7-sigma, statistically impossible
  for (int i = threadIdx.x; i < 128; i += 512) hist[i] = 0u;
  __syncthreads();
  for (int i = threadIdx.x; i < cnt; i += 512)
    atomicAdd(&hist[keyP[base + i] >> 19], 1u);
  __syncthreads();
  if (threadIdx.x == 0) {
    unsigned acc = 0u;
    for (int l = 0; l < 128; ++l) {
      starts[l] = acc;
      acc += (hist[l] + 3u) & ~3u;   // pad each node to multiple of 4
    }
    starts[128] = acc;
  }
  __syncthreads();
  unsigned tot = starts[128];
  for (int i = threadIdx.x; i < (int)tot; i += 512) { okey[i] = 0u; oval[i] = 0; }
  for (int l = threadIdx.x; l < 128; l += 512) cur[l] = starts[l];
  __syncthreads();
  for (int i = threadIdx.x; i < cnt; i += 512) {   // L2-hot re-read
    unsigned k = keyP[base + i];
    unsigned pos = atomicAdd(&cur[k >> 19], 1u);
    okey[pos] = k & 0x7FFFFu;
    oval[pos] = valP[base + i];
  }
  __syncthreads();

  // ---- aggregation from LDS ----
  int lane = threadIdx.x & 63;
  int wave = threadIdx.x >> 6;
  int g16 = lane >> 4;                      // entry subgroup 0..3
  int m = lane & 15;                        // column-slot group
  int nb0 = b * 128;
  int nodes = (N_U - nb0 < 128) ? (N_U - nb0) : 128;
  const unsigned short* tp = tmp5 + (m << 2);
  float bl = bias[lane];
  for (int l = wave; l < nodes; l += 8) {
    unsigned s = starts[l];
    unsigned e = starts[l + 1];
    float a0 = 0.f, a1 = 0.f, a2 = 0.f, a3 = 0.f;
    unsigned k = s;
    for (; k + 16 <= e; k += 16) {          // 4 gathers in flight
      unsigned key0 = okey[k + g16];
      unsigned key1 = okey[k + 4 + g16];
      unsigned key2 = okey[k + 8 + g16];
      unsigned key3 = okey[k + 12 + g16];
      float v0 = bf2f(oval[k + g16]);
      float v1 = bf2f(oval[k + 4 + g16]);
      float v2 = bf2f(oval[k + 8 + g16]);
      float v3 = bf2f(oval[k + 12 + g16]);
      ushort4 t0 = *(const ushort4*)(tp + (size_t)key0 * 64);
      ushort4 t1 = *(const ushort4*)(tp + (size_t)key1 * 64);
      ushort4 t2 = *(const ushort4*)(tp + (size_t)key2 * 64);
      ushort4 t3 = *(const ushort4*)(tp + (size_t)key3 * 64);
      a0 += v0 * bf2f(t0.x); a1 += v0 * bf2f(t0.y);
      a2 += v0 * bf2f(t0.z); a3 += v0 * bf2f(t0.w);
      a0 += v1 * bf2f(t1.x); a1 += v1 * bf2f(t1.y);
      a2 += v1 * bf2f(t1.z); a3 += v1 * bf2f(t1.w);
      a0 += v2 * bf2f(t2.x); a1 += v2 * bf2f(t2.y);
      a2 += v2 * bf2f(t2.z); a3 += v2 * bf2f(t2.w);
      a0 += v3 * bf2f(t3.x); a1 += v3 * bf2f(t3.y);
      a2 += v3 * bf2f(t3.z); a3 += v3 * bf2f(t3.w);
    }
    for (; k + 4 <= e; k += 4) {            // 0..3 remaining 4-entry groups
      unsigned key0 = okey[k + g16];
      float v0 = bf2f(oval[k + g16]);
      ushort4 t0 = *(const ushort4*)(tp + (size_t)key0 * 64);
      a0 += v0 * bf2f(t0.x); a1 += v0 * bf2f(t0.y);
      a2 += v0 * bf2f(t0.z); a3 += v0 * bf2f(t0.w);
    }
    a0 += __shfl_xor(a0, 16); a0 += __shfl_xor(a0, 32);
    a1 += __shfl_xor(a1, 16); a1 += __shfl_xor(a1, 32);
    a2 += __shfl_xor(a2, 16); a2 += __shfl_xor(a2, 32);
    a3 += __shfl_xor(a3, 16); a3 += __shfl_xor(a3, 32);
    float r = (g16 & 2) ? ((g16 & 1) ? a3 : a2) : ((g16 & 1) ? a1 : a0);
    out[(size_t)(nb0 + l) * 64 + lane] = fmaxf(r + bl, 0.f);
  }
}

// ===========================================================================
// FALLBACK PATH (proven R4 atomic-scatter version, used if ws is small)
// ===========================================================================
__global__ __launch_bounds__(256) void gemm_kernel(
    const float* __restrict__ X, const unsigned short* __restrict__ bfrag,
    unsigned short* __restrict__ tmp) {
  int lane = threadIdx.x & 63;
  int wave = threadIdx.x >> 6;
  int q = lane >> 4, m = lane & 15;
  bf16x8 bf[8];
#pragma unroll
  for (int f = 0; f < 8; ++f)
    bf[f] = *(const bf16x8*)(bfrag + (f * 64 + lane) * 8);
  int t = blockIdx.x * 4 + wave;
  if (t >= N_U / 16) return;
  int r0 = t * 16;
  const float* xr = X + (size_t)(r0 + m) * 64;
  float4 p0 = *(const float4*)(xr + q * 8);
  float4 p1 = *(const float4*)(xr + q * 8 + 4);
  float4 p2 = *(const float4*)(xr + 32 + q * 8);
  float4 p3 = *(const float4*)(xr + 32 + q * 8 + 4);
  bf16x8 a0, a1;
  a0[0] = (short)f2bf(p0.x); a0[1] = (short)f2bf(p0.y);
  a0[2] = (short)f2bf(p0.z); a0[3] = (short)f2bf(p0.w);
  a0[4] = (short)f2bf(p1.x); a0[5] = (short)f2bf(p1.y);
  a0[6] = (short)f2bf(p1.z); a0[7] = (short)f2bf(p1.w);
  a1[0] = (short)f2bf(p2.x); a1[1] = (short)f2bf(p2.y);
  a1[2] = (short)f2bf(p2.z); a1[3] = (short)f2bf(p2.w);
  a1[4] = (short)f2bf(p3.x); a1[5] = (short)f2bf(p3.y);
  a1[6] = (short)f2bf(p3.z); a1[7] = (short)f2bf(p3.w);
#pragma unroll
  for (int c = 0; c < 4; ++c) {
    f32x4 acc = {0.f, 0.f, 0.f, 0.f};
    acc = __builtin_amdgcn_mfma_f32_16x16x32_bf16(a0, bf[c * 2 + 0], acc, 0, 0, 0);
    acc = __builtin_amdgcn_mfma_f32_16x16x32_bf16(a1, bf[c * 2 + 1], acc, 0, 0, 0);
#pragma unroll
    for (int i = 0; i < 4; ++i)
      tmp[(size_t)(r0 + q * 4 + i) * 64 + c * 16 + m] = f2bf(acc[i]);
  }
}

__global__ __launch_bounds__(256) void scatter_kernel(
    const unsigned short* __restrict__ tmp, const float* __restrict__ edge_val,
    const int* __restrict__ dst_idx, const int* __restrict__ src_idx,
    float* __restrict__ z, int base, int cnt) {
  int e = blockIdx.x * 4 + (threadIdx.x >> 6);
  int j = threadIdx.x & 63;
  int d = dst_idx[e] - base;
  if ((unsigned)d >= (unsigned)cnt) return;
  int s = src_idx[e];
  float w = edge_val[e];
  atomicAdd(&z[(size_t)d * 64 + j], w * bf2f(tmp[(size_t)s * 64 + j]));
}

__global__ __launch_bounds__(256) void finalize_kernel(
    const float* __restrict__ z, const float* __restrict__ bias,
    float* __restrict__ out) {
  size_t i4 = ((size_t)blockIdx.x * 256 + threadIdx.x) * 4;
  float4 zz = *(const float4*)(z + i4);
  const float4 bb = *(const float4*)(bias + (i4 & 63));
  float4 o;
  o.x = fmaxf(zz.x + bb.x, 0.f);
  o.y = fmaxf(zz.y + bb.y, 0.f);
  o.z = fmaxf(zz.z + bb.z, 0.f);
  o.w = fmaxf(zz.w + bb.w, 0.f);
  *(float4*)(out + i4) = o;
}

extern "C" void kernel_launch(void* const* d_in, const int* in_sizes, int n_in,
                              void* d_out, int out_size, void* d_ws, size_t ws_size,
                              hipStream_t stream) {
  const float* x_u      = (const float*)d_in[0];
  const float* x_v      = (const float*)d_in[1];
  const float* w_u      = (const float*)d_in[2];
  const float* w_v      = (const float*)d_in[3];
  const float* bias_u   = (const float*)d_in[4];
  const float* bias_v   = (const float*)d_in[5];
  const float* edge_val = (const float*)d_in[6];
  const int*   edge_u   = (const int*)d_in[7];
  const int*   edge_v   = (const int*)d_in[8];
  float* out = (float*)d_out;
  char* ws = (char*)d_ws;

  // Fast-path ws layout (83.8 MB <= R5/R8-proven 84.9 MB):
  //   bfrag    @ 0           131,072
  //   tmp5     @ 131,072     64,000,000                 -> 64,131,072
  //   gcursor  @ 64,131,072  4,096                      -> 64,135,168
  //   (unused) @ 64,135,168  409,600                    -> 64,544,768
  //   keyP     @ 64,544,768  782*4096*4 = 12,812,288    -> 77,357,056
  //   valP     @ 77,357,056  782*4096*2 =  6,406,144    -> 83,763,200
  const size_t FAST_NEED = 83763200;

  unsigned short* bfrag = (unsigned short*)ws;
  prep_weights<<<2, 256, 0, stream>>>(w_u, w_v, bfrag);

  if (ws_size >= FAST_NEED) {
    unsigned short* tmp5      = (unsigned short*)(ws + 131072);
    unsigned*       gcursor   = (unsigned*)(ws + 64131072);
    unsigned*       keyP      = (unsigned*)(ws + 64544768);
    unsigned short* valP      = (unsigned short*)(ws + 77357056);

    const int edge_grid = (TOT_E + 8191) / 8192;  // 306
    const int gemm_grid = (N_U / 16 + 3) / 4;     // 1563

    for (int side = 0; side < 2; ++side) {
      // side 0: out_u <- tmp of x_v @ Wcum_v, dst=edge_u, src=edge_v
      // side 1: out_v <- tmp of x_u @ Wcum_u, dst=edge_v, src=edge_u
      const float* X = side ? x_u : x_v;
      const unsigned short* frag0 = bfrag + (side ? 0 : RR * 4096);
      const int* dst = side ? edge_v : edge_u;
      const int* src = side ? edge_u : edge_v;
      const float* bias = side ? bias_v : bias_u;
      float* out_side = out + (size_t)side * N_U * OO;

      init_cursor<<<4, 256, 0, stream>>>(gcursor);
      bucket_scatter<<<edge_grid, 1024, 0, stream>>>(dst, src, edge_val, gcursor,
                                                     keyP, valP);
      gemm5_kernel<<<gemm_grid, 256, 0, stream>>>(X, frag0, tmp5);
      bucket_sort_agg<<<NB, 512, 0, stream>>>(keyP, valP, gcursor, tmp5, bias,
                                              out_side);
    }
    return;
  }

  // ---------------- Fallback: proven R4 path ----------------
  unsigned short* tmp = (unsigned short*)(ws + 131072);
  float*          z   = (float*)(ws + 131072 + 12800000);
  const size_t fixed = 131072 + 12800000;
  size_t zbytes = ws_size > fixed ? ws_size - fixed : 0;
  long chunk = (long)(zbytes / (OO * 4));
  chunk -= chunk % 16;
  if (chunk < 16) chunk = 16;
  if (chunk > N_U) chunk = N_U;

  const int gemm_grid = (N_U / 16 + 3) / 4;
  const int scat_grid = EE / 4;

  for (int side = 0; side < 2; ++side) {
    const float* X = side ? x_u : x_v;
    const unsigned short* frag0 = bfrag + (side ? 0 : RR * 4096);
    const int* dst = side ? edge_v : edge_u;
    const int* src = side ? edge_u : edge_v;
    const float* bias = side ? bias_v : bias_u;
    float* out_side = out + (size_t)side * N_U * OO;

    for (long base = 0; base < N_U; base += chunk) {
      long cnt = N_U - base < chunk ? N_U - base : chunk;
      hipMemsetAsync(z, 0, (size_t)cnt * OO * 4, stream);
      for (int r = 0; r < RR; ++r) {
        gemm_kernel<<<gemm_grid, 256, 0, stream>>>(X, frag0 + r * 4096, tmp);
        scatter_kernel<<<scat_grid, 256, 0, stream>>>(
            tmp, edge_val + (size_t)r * EE, dst + (size_t)r * EE,
            src + (size_t)r * EE, z, (int)base, (int)cnt);
      }
      finalize_kernel<<<(int)(cnt / 16), 256, 0, stream>>>(
          z, bias, out_side + base * OO);
    }
  }
}

// Round 10
// 322.150 us; speedup vs baseline: 1.1319x; 1.0489x over previous
//
#include <hip/hip_runtime.h>

// Problem constants (from reference)
#define N_U 100000
#define N_V 100000
#define OO 64
#define RR 5
#define EE 500000
#define TOT_E (RR * EE)   // 2,500,000 edges per direction (TOT_E % 8 == 0)
#define NB 782            // buckets of 128 dst nodes (781*128=99968, last=32)
#define CAP 4096          // payload window stride per bucket (entries)
#define CAPU 3584         // max entries per bucket (mean 3197, +6.8 sigma)
#define SCAT_BLOCKS 306   // ceil(TOT_E / 8192)
#define GEMM_BLOCKS 391   // ceil(6250 tiles / 16 waves)

typedef short bf16x8 __attribute__((ext_vector_type(8)));
typedef float f32x4 __attribute__((ext_vector_type(4)));

__device__ __forceinline__ float bf2f(unsigned short u) {
  union { unsigned int i; float f; } x;
  x.i = ((unsigned int)u) << 16;
  return x.f;
}
__device__ __forceinline__ unsigned short f2bf(float f) {
  union { float f; unsigned int i; } x;
  x.f = f;
  unsigned int lsb = (x.i >> 16) & 1u;
  unsigned int r = x.i + 0x7fffu + lsb;   // round-to-nearest-even
  return (unsigned short)(r >> 16);
}

// ---------------------------------------------------------------------------
// Cumsum the per-relation fp32 weights, write bf16 in MFMA B-fragment order.
// bfrag layout: [side(2)=u,v][r(5)][4096]. Also inits both sides' gcursor
// windows (gcur may be null in the fallback path).
// ---------------------------------------------------------------------------
__global__ void prep_weights(const float* __restrict__ wu,
                             const float* __restrict__ wv,
                             unsigned short* __restrict__ bfrag,
                             unsigned* __restrict__ gcur) {
  int side = blockIdx.x;
  if (gcur) {
    unsigned* g = gcur + side * 1024;
    for (int i = threadIdx.x; i < NB; i += 256) g[i] = (unsigned)i * CAP;
  }
  const float* w = side ? wv : wu;
  for (int idx = threadIdx.x; idx < 4096; idx += 256) {
    int d = idx >> 6, o = idx & 63;
    int c = o >> 4, n = o & 15;
    int sk = d >> 5, q = (d >> 3) & 3, jj = d & 7;
    int f = c * 2 + sk;
    int lane = q * 16 + n;
    int pos = (f * 64 + lane) * 8 + jj;
    float acc = 0.f;
    for (int r = 0; r < RR; ++r) {
      acc += w[r * 4096 + idx];
      bfrag[(side * RR + r) * 4096 + pos] = f2bf(acc);
    }
  }
}

// ---------------------------------------------------------------------------
// FUSED scatter + gemm: independent phases of one side overlapped in a
// single heterogeneous launch. Blocks [0,306) run the proven LDS-staged
// coalesced multi-split scatter (1024 thr); blocks [306,697) run the
// all-5-relations GEMM at 16 waves/block (16 row-tiles). The gemm's compute
// fills the scatter waves' memory-stall issue slots on shared CUs.
// LDS is a manual union: scatter needs 75.9 KB, gemm 40 KB -> one 75.9 KB
// buffer, 2 blocks/CU (unchanged from the standalone scatter).
// gemm B-preload vectorized bf16x8 (was scalar ushort: 8x fewer loads).
// ---------------------------------------------------------------------------
__global__ __launch_bounds__(1024) void scatter_gemm(
    const int* __restrict__ dst, const int* __restrict__ src,
    const float* __restrict__ val, unsigned* __restrict__ gcursor,
    unsigned* __restrict__ keyP, unsigned short* __restrict__ valP,
    const float* __restrict__ X,
    const unsigned short* __restrict__ bfrag_side,  // [r(5)][4096]
    unsigned short* __restrict__ tmp5) {            // [r(5)][100000][64]
  __shared__ unsigned lds_u32[18972];   // 75,888 B union
  int blk = blockIdx.x;
  int tid = threadIdx.x;
  if (blk < SCAT_BLOCKS) {
    // ---------------- scatter path (proven R5 body, aliased LDS) ----------
    unsigned* skey = lds_u32;                                    // 8192 u32
    unsigned short* sval = (unsigned short*)(lds_u32 + 8192);    // 8192 u16
    unsigned short* sbid = (unsigned short*)(lds_u32 + 12288);   // 8192 u16
    unsigned* cnt  = lds_u32 + 16384;                            // 782
    unsigned* sc   = lds_u32 + 17166;                            // 1024
    unsigned* gbase = lds_u32 + 18190;                           // 782
    for (int i = tid; i < NB; i += 1024) cnt[i] = 0u;
    __syncthreads();
    int base = blk * 8192;
    int t8 = base + tid * 8;
    bool full = (t8 < TOT_E);
    if (full) {
      int4 d0 = *(const int4*)(dst + t8);
      int4 d1 = *(const int4*)(dst + t8 + 4);
      atomicAdd(&cnt[d0.x >> 7], 1u);
      atomicAdd(&cnt[d0.y >> 7], 1u);
      atomicAdd(&cnt[d0.z >> 7], 1u);
      atomicAdd(&cnt[d0.w >> 7], 1u);
      atomicAdd(&cnt[d1.x >> 7], 1u);
      atomicAdd(&cnt[d1.y >> 7], 1u);
      atomicAdd(&cnt[d1.z >> 7], 1u);
      atomicAdd(&cnt[d1.w >> 7], 1u);
    }
    __syncthreads();
    // inclusive scan of cnt (NB entries, zero-padded to 1024)
    sc[tid] = (tid < NB) ? cnt[tid] : 0u;
    __syncthreads();
    for (int off = 1; off < 1024; off <<= 1) {
      unsigned a = sc[tid];
      unsigned b = (tid >= off) ? sc[tid - off] : 0u;
      __syncthreads();
      sc[tid] = a + b;
      __syncthreads();
    }
    for (int b = tid; b < NB; b += 1024) {
      unsigned c = cnt[b];
      gbase[b] = c ? atomicAdd(&gcursor[b], c) : 0u;
      cnt[b] = sc[b] - c;
    }
    __syncthreads();
    unsigned total = sc[NB - 1];
    __syncthreads();
    for (int b = tid; b < NB; b += 1024) sc[b] = cnt[b];   // local cursors
    __syncthreads();
    if (full) {
      int4 d0 = *(const int4*)(dst + t8);
      int4 d1 = *(const int4*)(dst + t8 + 4);
      int4 s0 = *(const int4*)(src + t8);
      int4 s1 = *(const int4*)(src + t8 + 4);
      float4 v0 = *(const float4*)(val + t8);
      float4 v1 = *(const float4*)(val + t8 + 4);
      unsigned rb = (unsigned)(t8 / EE) * N_U;
#define PUT(dd, ss, vv)                                                     \
      {                                                                     \
        int bb = (dd) >> 7;                                                 \
        unsigned pos = atomicAdd(&sc[bb], 1u);                              \
        skey[pos] = (((unsigned)((dd) & 127)) << 19) | (rb + (unsigned)(ss)); \
        sval[pos] = f2bf(vv);                                               \
        sbid[pos] = (unsigned short)bb;                                     \
      }
      PUT(d0.x, s0.x, v0.x)
      PUT(d0.y, s0.y, v0.y)
      PUT(d0.z, s0.z, v0.z)
      PUT(d0.w, s0.w, v0.w)
      PUT(d1.x, s1.x, v1.x)
      PUT(d1.y, s1.y, v1.y)
      PUT(d1.z, s1.z, v1.z)
      PUT(d1.w, s1.w, v1.w)
#undef PUT
    }
    __syncthreads();
    // coalesced flush: consecutive i -> consecutive addr within each run
    for (int i = tid; i < (int)total; i += 1024) {
      unsigned b = sbid[i];
      unsigned addr = gbase[b] + ((unsigned)i - cnt[b]);
      keyP[addr] = skey[i];
      valP[addr] = sval[i];
    }
  } else {
    // ---------------- gemm path (proven gemm5 body, 16 waves/block) -------
    unsigned short* smem = (unsigned short*)lds_u32;   // 20480 u16 = 40 KB
    for (int i = tid; i < 2560; i += 1024)             // bf16x8 preload
      ((bf16x8*)smem)[i] = ((const bf16x8*)bfrag_side)[i];
    __syncthreads();
    int lane = tid & 63;
    int wave = tid >> 6;
    int q = lane >> 4, m = lane & 15;
    int t = (blk - SCAT_BLOCKS) * 16 + wave;
    if (t >= N_U / 16) return;
    int r0 = t * 16;
    const float* xr = X + (size_t)(r0 + m) * 64;
    float4 p0 = *(const float4*)(xr + q * 8);
    float4 p1 = *(const float4*)(xr + q * 8 + 4);
    float4 p2 = *(const float4*)(xr + 32 + q * 8);
    float4 p3 = *(const float4*)(xr + 32 + q * 8 + 4);
    bf16x8 a0, a1;
    a0[0] = (short)f2bf(p0.x); a0[1] = (short)f2bf(p0.y);
    a0[2] = (short)f2bf(p0.z); a0[3] = (short)f2bf(p0.w);
    a0[4] = (short)f2bf(p1.x); a0[5] = (short)f2bf(p1.y);
    a0[6] = (short)f2bf(p1.z); a0[7] = (short)f2bf(p1.w);
    a1[0] = (short)f2bf(p2.x); a1[1] = (short)f2bf(p2.y);
    a1[2] = (short)f2bf(p2.z); a1[3] = (short)f2bf(p2.w);
    a1[4] = (short)f2bf(p3.x); a1[5] = (short)f2bf(p3.y);
    a1[6] = (short)f2bf(p3.z); a1[7] = (short)f2bf(p3.w);
    for (int r = 0; r < RR; ++r) {
      f32x4 acc[4];
#pragma unroll
      for (int c = 0; c < 4; ++c) {
        bf16x8 b0 = *(const bf16x8*)(smem + r * 4096 + ((c * 2 + 0) * 64 + lane) * 8);
        bf16x8 b1 = *(const bf16x8*)(smem + r * 4096 + ((c * 2 + 1) * 64 + lane) * 8);
        f32x4 a = {0.f, 0.f, 0.f, 0.f};
        a = __builtin_amdgcn_mfma_f32_16x16x32_bf16(a0, b0, a, 0, 0, 0);
        a = __builtin_amdgcn_mfma_f32_16x16x32_bf16(a1, b1, a, 0, 0, 0);
        acc[c] = a;
      }
      unsigned short* trow = tmp5 + (size_t)r * N_U * 64;
#pragma unroll
      for (int i = 0; i < 4; ++i) {
        ushort4 o;
        o.x = f2bf(acc[0][i]); o.y = f2bf(acc[1][i]);
        o.z = f2bf(acc[2][i]); o.w = f2bf(acc[3][i]);
        *(ushort4*)(trow + (size_t)(r0 + q * 4 + i) * 64 + m * 4) = o;
      }
    }
  }
}

// ---------------------------------------------------------------------------
// MERGED sort + aggregate (proven R5 form, 2-deep unroll — R8 proved 4-deep
// is neutral, so per-wave MLP is not the limiter; keep the simpler body).
// One block per bucket, 512 threads, two-pass low-LDS sort; agg: 8 waves,
// wave handles every-8th node; 16-lane group g16 reads its group's key/val
// via broadcast ds_read, gathers the 128-B tmp5 row (ushort4/lane),
// register-FMA; 2-round shfl_xor(16,32) reduce; lane L writes column L.
// LDS: 16384+8192+512+516+512 = 25.6 KB -> wave-capped 4 blocks/CU.
// ---------------------------------------------------------------------------
__global__ __launch_bounds__(512, 8) void bucket_sort_agg(
    const unsigned* __restrict__ keyP, const unsigned short* __restrict__ valP,
    const unsigned* __restrict__ gcursor,
    const unsigned short* __restrict__ tmp5,
    const float* __restrict__ bias, float* __restrict__ out) {
  __shared__ unsigned okey[CAP];           // sorted+padded (max cnt+384 <= 3968)
  __shared__ unsigned short oval[CAP];
  __shared__ unsigned hist[128];
  __shared__ unsigned starts[129];
  __shared__ unsigned cur[128];
  int b = blockIdx.x;
  unsigned base = (unsigned)b * CAP;
  int cnt = (int)(gcursor[b] - base);
  if (cnt > CAPU) cnt = CAPU;   // ~7-sigma, statistically impossible
  for (int i = threadIdx.x; i < 128; i += 512) hist[i] = 0u;
  __syncthreads();
  for (int i = threadIdx.x; i < cnt; i += 512)
    atomicAdd(&hist[keyP[base + i] >> 19], 1u);
  __syncthreads();
  if (threadIdx.x == 0) {
    unsigned acc = 0u;
    for (int l = 0; l < 128; ++l) {
      starts[l] = acc;
      acc += (hist[l] + 3u) & ~3u;   // pad each node to multiple of 4
    }
    starts[128] = acc;
  }
  __syncthreads();
  unsigned tot = starts[128];
  for (int i = threadIdx.x; i < (int)tot; i += 512) { okey[i] = 0u; oval[i] = 0; }
  for (int l = threadIdx.x; l < 128; l += 512) cur[l] = starts[l];
  __syncthreads();
  for (int i = threadIdx.x; i < cnt; i += 512) {   // L2-hot re-read
    unsigned k = keyP[base + i];
    unsigned pos = atomicAdd(&cur[k >> 19], 1u);
    okey[pos] = k & 0x7FFFFu;
    oval[pos] = valP[base + i];
  }
  __syncthreads();

  // ---- aggregation from LDS ----
  int lane = threadIdx.x & 63;
  int wave = threadIdx.x >> 6;
  int g16 = lane >> 4;                      // entry subgroup 0..3
  int m = lane & 15;                        // column-slot group
  int nb0 = b * 128;
  int nodes = (N_U - nb0 < 128) ? (N_U - nb0) : 128;
  const unsigned short* tp = tmp5 + (m << 2);
  float bl = bias[lane];
  for (int l = wave; l < nodes; l += 8) {
    unsigned s = starts[l];
    unsigned e = starts[l + 1];
    float a0 = 0.f, a1 = 0.f, a2 = 0.f, a3 = 0.f;
    unsigned k = s;
    for (; k + 8 <= e; k += 8) {            // 2 gathers in flight
      unsigned key0 = okey[k + g16];
      unsigned key1 = okey[k + 4 + g16];
      float v0 = bf2f(oval[k + g16]);
      float v1 = bf2f(oval[k + 4 + g16]);
      ushort4 t0 = *(const ushort4*)(tp + (size_t)key0 * 64);
      ushort4 t1 = *(const ushort4*)(tp + (size_t)key1 * 64);
      a0 += v0 * bf2f(t0.x);
      a1 += v0 * bf2f(t0.y);
      a2 += v0 * bf2f(t0.z);
      a3 += v0 * bf2f(t0.w);
      a0 += v1 * bf2f(t1.x);
      a1 += v1 * bf2f(t1.y);
      a2 += v1 * bf2f(t1.z);
      a3 += v1 * bf2f(t1.w);
    }
    if (k < e) {                            // padded remainder: one group
      unsigned key0 = okey[k + g16];
      float v0 = bf2f(oval[k + g16]);
      ushort4 t0 = *(const ushort4*)(tp + (size_t)key0 * 64);
      a0 += v0 * bf2f(t0.x);
      a1 += v0 * bf2f(t0.y);
      a2 += v0 * bf2f(t0.z);
      a3 += v0 * bf2f(t0.w);
    }
    a0 += __shfl_xor(a0, 16); a0 += __shfl_xor(a0, 32);
    a1 += __shfl_xor(a1, 16); a1 += __shfl_xor(a1, 32);
    a2 += __shfl_xor(a2, 16); a2 += __shfl_xor(a2, 32);
    a3 += __shfl_xor(a3, 16); a3 += __shfl_xor(a3, 32);
    float r = (g16 & 2) ? ((g16 & 1) ? a3 : a2) : ((g16 & 1) ? a1 : a0);
    out[(size_t)(nb0 + l) * 64 + lane] = fmaxf(r + bl, 0.f);
  }
}

// ===========================================================================
// FALLBACK PATH (proven R4 atomic-scatter version, used if ws is small)
// ===========================================================================
__global__ __launch_bounds__(256) void gemm_kernel(
    const float* __restrict__ X, const unsigned short* __restrict__ bfrag,
    unsigned short* __restrict__ tmp) {
  int lane = threadIdx.x & 63;
  int wave = threadIdx.x >> 6;
  int q = lane >> 4, m = lane & 15;
  bf16x8 bf[8];
#pragma unroll
  for (int f = 0; f < 8; ++f)
    bf[f] = *(const bf16x8*)(bfrag + (f * 64 + lane) * 8);
  int t = blockIdx.x * 4 + wave;
  if (t >= N_U / 16) return;
  int r0 = t * 16;
  const float* xr = X + (size_t)(r0 + m) * 64;
  float4 p0 = *(const float4*)(xr + q * 8);
  float4 p1 = *(const float4*)(xr + q * 8 + 4);
  float4 p2 = *(const float4*)(xr + 32 + q * 8);
  float4 p3 = *(const float4*)(xr + 32 + q * 8 + 4);
  bf16x8 a0, a1;
  a0[0] = (short)f2bf(p0.x); a0[1] = (short)f2bf(p0.y);
  a0[2] = (short)f2bf(p0.z); a0[3] = (short)f2bf(p0.w);
  a0[4] = (short)f2bf(p1.x); a0[5] = (short)f2bf(p1.y);
  a0[6] = (short)f2bf(p1.z); a0[7] = (short)f2bf(p1.w);
  a1[0] = (short)f2bf(p2.x); a1[1] = (short)f2bf(p2.y);
  a1[2] = (short)f2bf(p2.z); a1[3] = (short)f2bf(p2.w);
  a1[4] = (short)f2bf(p3.x); a1[5] = (short)f2bf(p3.y);
  a1[6] = (short)f2bf(p3.z); a1[7] = (short)f2bf(p3.w);
#pragma unroll
  for (int c = 0; c < 4; ++c) {
    f32x4 acc = {0.f, 0.f, 0.f, 0.f};
    acc = __builtin_amdgcn_mfma_f32_16x16x32_bf16(a0, bf[c * 2 + 0], acc, 0, 0, 0);
    acc = __builtin_amdgcn_mfma_f32_16x16x32_bf16(a1, bf[c * 2 + 1], acc, 0, 0, 0);
#pragma unroll
    for (int i = 0; i < 4; ++i)
      tmp[(size_t)(r0 + q * 4 + i) * 64 + c * 16 + m] = f2bf(acc[i]);
  }
}

__global__ __launch_bounds__(256) void scatter_kernel(
    const unsigned short* __restrict__ tmp, const float* __restrict__ edge_val,
    const int* __restrict__ dst_idx, const int* __restrict__ src_idx,
    float* __restrict__ z, int base, int cnt) {
  int e = blockIdx.x * 4 + (threadIdx.x >> 6);
  int j = threadIdx.x & 63;
  int d = dst_idx[e] - base;
  if ((unsigned)d >= (unsigned)cnt) return;
  int s = src_idx[e];
  float w = edge_val[e];
  atomicAdd(&z[(size_t)d * 64 + j], w * bf2f(tmp[(size_t)s * 64 + j]));
}

__global__ __launch_bounds__(256) void finalize_kernel(
    const float* __restrict__ z, const float* __restrict__ bias,
    float* __restrict__ out) {
  size_t i4 = ((size_t)blockIdx.x * 256 + threadIdx.x) * 4;
  float4 zz = *(const float4*)(z + i4);
  const float4 bb = *(const float4*)(bias + (i4 & 63));
  float4 o;
  o.x = fmaxf(zz.x + bb.x, 0.f);
  o.y = fmaxf(zz.y + bb.y, 0.f);
  o.z = fmaxf(zz.z + bb.z, 0.f);
  o.w = fmaxf(zz.w + bb.w, 0.f);
  *(float4*)(out + i4) = o;
}

extern "C" void kernel_launch(void* const* d_in, const int* in_sizes, int n_in,
                              void* d_out, int out_size, void* d_ws, size_t ws_size,
                              hipStream_t stream) {
  const float* x_u      = (const float*)d_in[0];
  const float* x_v      = (const float*)d_in[1];
  const float* w_u      = (const float*)d_in[2];
  const float* w_v      = (const float*)d_in[3];
  const float* bias_u   = (const float*)d_in[4];
  const float* bias_v   = (const float*)d_in[5];
  const float* edge_val = (const float*)d_in[6];
  const int*   edge_u   = (const int*)d_in[7];
  const int*   edge_v   = (const int*)d_in[8];
  float* out = (float*)d_out;
  char* ws = (char*)d_ws;

  // Fast-path ws layout (83.8 MB <= proven 84.9 MB):
  //   bfrag    @ 0           131,072
  //   tmp5     @ 131,072     64,000,000                 -> 64,131,072
  //   gcur[2]  @ 64,131,072  2*4,096                    -> 64,139,264
  //   (unused) @ 64,139,264  405,504                    -> 64,544,768
  //   keyP     @ 64,544,768  782*4096*4 = 12,812,288    -> 77,357,056
  //   valP     @ 77,357,056  782*4096*2 =  6,406,144    -> 83,763,200
  const size_t FAST_NEED = 83763200;

  unsigned short* bfrag = (unsigned short*)ws;

  if (ws_size >= FAST_NEED) {
    unsigned short* tmp5 = (unsigned short*)(ws + 131072);
    unsigned*       gcur = (unsigned*)(ws + 64131072);   // [2][1024]
    unsigned*       keyP = (unsigned*)(ws + 64544768);
    unsigned short* valP = (unsigned short*)(ws + 77357056);

    prep_weights<<<2, 256, 0, stream>>>(w_u, w_v, bfrag, gcur);

    for (int side = 0; side < 2; ++side) {
      // side 0: out_u <- tmp of x_v @ Wcum_v, dst=edge_u, src=edge_v
      // side 1: out_v <- tmp of x_u @ Wcum_u, dst=edge_v, src=edge_u
      const float* X = side ? x_u : x_v;
      const unsigned short* frag0 = bfrag + (side ? 0 : RR * 4096);
      const int* dst = side ? edge_v : edge_u;
      const int* src = side ? edge_u : edge_v;
      const float* bias = side ? bias_v : bias_u;
      float* out_side = out + (size_t)side * N_U * OO;
      unsigned* gc = gcur + side * 1024;

      scatter_gemm<<<SCAT_BLOCKS + GEMM_BLOCKS, 1024, 0, stream>>>(
          dst, src, edge_val, gc, keyP, valP, X, frag0, tmp5);
      bucket_sort_agg<<<NB, 512, 0, stream>>>(keyP, valP, gc, tmp5, bias,
                                              out_side);
    }
    return;
  }

  // ---------------- Fallback: proven R4 path ----------------
  prep_weights<<<2, 256, 0, stream>>>(w_u, w_v, bfrag, (unsigned*)0);

  unsigned short* tmp = (unsigned short*)(ws + 131072);
  float*          z   = (float*)(ws + 131072 + 12800000);
  const size_t fixed = 131072 + 12800000;
  size_t zbytes = ws_size > fixed ? ws_size - fixed : 0;
  long chunk = (long)(zbytes / (OO * 4));
  chunk -= chunk % 16;
  if (chunk < 16) chunk = 16;
  if (chunk > N_U) chunk = N_U;

  const int gemm_grid = (N_U / 16 + 3) / 4;
  const int scat_grid = EE / 4;

  for (int side = 0; side < 2; ++side) {
    const float* X = side ? x_u : x_v;
    const unsigned short* frag0 = bfrag + (side ? 0 : RR * 4096);
    const int* dst = side ? edge_v : edge_u;
    const int* src = side ? edge_u : edge_v;
    const float* bias = side ? bias_v : bias_u;
    float* out_side = out + (size_t)side * N_U * OO;

    for (long base = 0; base < N_U; base += chunk) {
      long cnt = N_U - base < chunk ? N_U - base : chunk;
      hipMemsetAsync(z, 0, (size_t)cnt * OO * 4, stream);
      for (int r = 0; r < RR; ++r) {
        gemm_kernel<<<gemm_grid, 256, 0, stream>>>(X, frag0 + r * 4096, tmp);
        scatter_kernel<<<scat_grid, 256, 0, stream>>>(
            tmp, edge_val + (size_t)r * EE, dst + (size_t)r * EE,
            src + (size_t)r * EE, z, (int)base, (int)cnt);
      }
      finalize_kernel<<<(int)(cnt / 16), 256, 0, stream>>>(
          z, bias, out_side + base * OO);
    }
  }
}

// Round 11
// 316.259 us; speedup vs baseline: 1.1530x; 1.0186x over previous
//
#include <hip/hip_runtime.h>

// Problem constants (from reference)
#define N_U 100000
#define N_V 100000
#define OO 64
#define RR 5
#define EE 500000
#define TOT_E (RR * EE)   // 2,500,000 edges per direction (TOT_E % 8 == 0)
#define NB 782            // buckets of 128 dst nodes (781*128=99968, last=32)
#define CAP 4096          // payload window stride per bucket (entries)
#define CAPU 3584         // max entries per bucket (mean 3197, +6.8 sigma)
#define SCAT_BLOCKS 306   // ceil(TOT_E / 8192)
#define GEMM_BLOCKS 391   // ceil(6250 tiles / 16 waves)

typedef short bf16x8 __attribute__((ext_vector_type(8)));
typedef float f32x4 __attribute__((ext_vector_type(4)));

__device__ __forceinline__ float bf2f(unsigned short u) {
  union { unsigned int i; float f; } x;
  x.i = ((unsigned int)u) << 16;
  return x.f;
}
__device__ __forceinline__ unsigned short f2bf(float f) {
  union { float f; unsigned int i; } x;
  x.f = f;
  unsigned int lsb = (x.i >> 16) & 1u;
  unsigned int r = x.i + 0x7fffu + lsb;   // round-to-nearest-even
  return (unsigned short)(r >> 16);
}

// ---------------------------------------------------------------------------
// Cumsum the per-relation fp32 weights, write bf16 in MFMA B-fragment order.
// bfrag layout: [side(2)=u,v][r(5)][4096]. Also inits both sides' gcursor
// windows (gcur may be null in the fallback path).
// ---------------------------------------------------------------------------
__global__ void prep_weights(const float* __restrict__ wu,
                             const float* __restrict__ wv,
                             unsigned short* __restrict__ bfrag,
                             unsigned* __restrict__ gcur) {
  int side = blockIdx.x;
  if (gcur) {
    unsigned* g = gcur + side * 1024;
    for (int i = threadIdx.x; i < NB; i += 256) g[i] = (unsigned)i * CAP;
  }
  const float* w = side ? wv : wu;
  for (int idx = threadIdx.x; idx < 4096; idx += 256) {
    int d = idx >> 6, o = idx & 63;
    int c = o >> 4, n = o & 15;
    int sk = d >> 5, q = (d >> 3) & 3, jj = d & 7;
    int f = c * 2 + sk;
    int lane = q * 16 + n;
    int pos = (f * 64 + lane) * 8 + jj;
    float acc = 0.f;
    for (int r = 0; r < RR; ++r) {
      acc += w[r * 4096 + idx];
      bfrag[(side * RR + r) * 4096 + pos] = f2bf(acc);
    }
  }
}

// ---------------------------------------------------------------------------
// MEGA heterogeneous kernel: blocks [0,nS0) run the LDS-staged coalesced
// multi-split scatter for side A (dst0/src0 -> keyP0/valP0/gcur0); blocks
// [nS0,nS0+nS1) the same for side B; remaining blocks run the
// all-5-relations GEMM at 16 waves/block. All three phases are mutually
// independent, so one launch overlaps them: GEMM compute fills the scatter
// waves' memory-stall slots. Launch (306,306,391) for the big step, and
// (0,0,391) for the standalone side-0 GEMM.
// LDS union: scatter 75.9 KB / gemm 40 KB -> 75.9 KB, 2 blocks/CU.
// ---------------------------------------------------------------------------
__global__ __launch_bounds__(1024) void mega(
    const int* __restrict__ dst0, const int* __restrict__ src0,
    const int* __restrict__ dst1, const int* __restrict__ src1,
    const float* __restrict__ val,
    unsigned* __restrict__ gcur0, unsigned* __restrict__ keyP0,
    unsigned short* __restrict__ valP0,
    unsigned* __restrict__ gcur1, unsigned* __restrict__ keyP1,
    unsigned short* __restrict__ valP1,
    const float* __restrict__ X,
    const unsigned short* __restrict__ bfrag_side,  // [r(5)][4096]
    unsigned short* __restrict__ tmp5,              // [r(5)][100000][64]
    int nS0, int nS1) {
  __shared__ unsigned lds_u32[18972];   // 75,888 B union
  int blk = blockIdx.x;
  int tid = threadIdx.x;
  if (blk < nS0 + nS1) {
    // ---------------- scatter path (proven body, side-parameterized) ------
    bool sB = (blk >= nS0);
    const int* dst = sB ? dst1 : dst0;
    const int* src = sB ? src1 : src0;
    unsigned* gcursor = sB ? gcur1 : gcur0;
    unsigned* keyP = sB ? keyP1 : keyP0;
    unsigned short* valP = sB ? valP1 : valP0;
    int sblk = sB ? blk - nS0 : blk;

    unsigned* skey = lds_u32;                                    // 8192 u32
    unsigned short* sval = (unsigned short*)(lds_u32 + 8192);    // 8192 u16
    unsigned short* sbid = (unsigned short*)(lds_u32 + 12288);   // 8192 u16
    unsigned* cnt  = lds_u32 + 16384;                            // 782
    unsigned* sc   = lds_u32 + 17166;                            // 1024
    unsigned* gbase = lds_u32 + 18190;                           // 782
    for (int i = tid; i < NB; i += 1024) cnt[i] = 0u;
    __syncthreads();
    int base = sblk * 8192;
    int t8 = base + tid * 8;
    bool full = (t8 < TOT_E);
    if (full) {
      int4 d0 = *(const int4*)(dst + t8);
      int4 d1 = *(const int4*)(dst + t8 + 4);
      atomicAdd(&cnt[d0.x >> 7], 1u);
      atomicAdd(&cnt[d0.y >> 7], 1u);
      atomicAdd(&cnt[d0.z >> 7], 1u);
      atomicAdd(&cnt[d0.w >> 7], 1u);
      atomicAdd(&cnt[d1.x >> 7], 1u);
      atomicAdd(&cnt[d1.y >> 7], 1u);
      atomicAdd(&cnt[d1.z >> 7], 1u);
      atomicAdd(&cnt[d1.w >> 7], 1u);
    }
    __syncthreads();
    // inclusive scan of cnt (NB entries, zero-padded to 1024)
    sc[tid] = (tid < NB) ? cnt[tid] : 0u;
    __syncthreads();
    for (int off = 1; off < 1024; off <<= 1) {
      unsigned a = sc[tid];
      unsigned b = (tid >= off) ? sc[tid - off] : 0u;
      __syncthreads();
      sc[tid] = a + b;
      __syncthreads();
    }
    for (int b = tid; b < NB; b += 1024) {
      unsigned c = cnt[b];
      gbase[b] = c ? atomicAdd(&gcursor[b], c) : 0u;
      cnt[b] = sc[b] - c;
    }
    __syncthreads();
    unsigned total = sc[NB - 1];
    __syncthreads();
    for (int b = tid; b < NB; b += 1024) sc[b] = cnt[b];   // local cursors
    __syncthreads();
    if (full) {
      int4 d0 = *(const int4*)(dst + t8);
      int4 d1 = *(const int4*)(dst + t8 + 4);
      int4 s0 = *(const int4*)(src + t8);
      int4 s1 = *(const int4*)(src + t8 + 4);
      float4 v0 = *(const float4*)(val + t8);
      float4 v1 = *(const float4*)(val + t8 + 4);
      unsigned rb = (unsigned)(t8 / EE) * N_U;
#define PUT(dd, ss, vv)                                                     \
      {                                                                     \
        int bb = (dd) >> 7;                                                 \
        unsigned pos = atomicAdd(&sc[bb], 1u);                              \
        skey[pos] = (((unsigned)((dd) & 127)) << 19) | (rb + (unsigned)(ss)); \
        sval[pos] = f2bf(vv);                                               \
        sbid[pos] = (unsigned short)bb;                                     \
      }
      PUT(d0.x, s0.x, v0.x)
      PUT(d0.y, s0.y, v0.y)
      PUT(d0.z, s0.z, v0.z)
      PUT(d0.w, s0.w, v0.w)
      PUT(d1.x, s1.x, v1.x)
      PUT(d1.y, s1.y, v1.y)
      PUT(d1.z, s1.z, v1.z)
      PUT(d1.w, s1.w, v1.w)
#undef PUT
    }
    __syncthreads();
    // coalesced flush: consecutive i -> consecutive addr within each run
    for (int i = tid; i < (int)total; i += 1024) {
      unsigned b = sbid[i];
      unsigned addr = gbase[b] + ((unsigned)i - cnt[b]);
      keyP[addr] = skey[i];
      valP[addr] = sval[i];
    }
  } else {
    // ---------------- gemm path (proven body, 16 waves/block) -------------
    unsigned short* smem = (unsigned short*)lds_u32;   // 20480 u16 = 40 KB
    for (int i = tid; i < 2560; i += 1024)             // bf16x8 preload
      ((bf16x8*)smem)[i] = ((const bf16x8*)bfrag_side)[i];
    __syncthreads();
    int lane = tid & 63;
    int wave = tid >> 6;
    int q = lane >> 4, m = lane & 15;
    int t = (blk - nS0 - nS1) * 16 + wave;
    if (t >= N_U / 16) return;
    int r0 = t * 16;
    const float* xr = X + (size_t)(r0 + m) * 64;
    float4 p0 = *(const float4*)(xr + q * 8);
    float4 p1 = *(const float4*)(xr + q * 8 + 4);
    float4 p2 = *(const float4*)(xr + 32 + q * 8);
    float4 p3 = *(const float4*)(xr + 32 + q * 8 + 4);
    bf16x8 a0, a1;
    a0[0] = (short)f2bf(p0.x); a0[1] = (short)f2bf(p0.y);
    a0[2] = (short)f2bf(p0.z); a0[3] = (short)f2bf(p0.w);
    a0[4] = (short)f2bf(p1.x); a0[5] = (short)f2bf(p1.y);
    a0[6] = (short)f2bf(p1.z); a0[7] = (short)f2bf(p1.w);
    a1[0] = (short)f2bf(p2.x); a1[1] = (short)f2bf(p2.y);
    a1[2] = (short)f2bf(p2.z); a1[3] = (short)f2bf(p2.w);
    a1[4] = (short)f2bf(p3.x); a1[5] = (short)f2bf(p3.y);
    a1[6] = (short)f2bf(p3.z); a1[7] = (short)f2bf(p3.w);
    for (int r = 0; r < RR; ++r) {
      f32x4 acc[4];
#pragma unroll
      for (int c = 0; c < 4; ++c) {
        bf16x8 b0 = *(const bf16x8*)(smem + r * 4096 + ((c * 2 + 0) * 64 + lane) * 8);
        bf16x8 b1 = *(const bf16x8*)(smem + r * 4096 + ((c * 2 + 1) * 64 + lane) * 8);
        f32x4 a = {0.f, 0.f, 0.f, 0.f};
        a = __builtin_amdgcn_mfma_f32_16x16x32_bf16(a0, b0, a, 0, 0, 0);
        a = __builtin_amdgcn_mfma_f32_16x16x32_bf16(a1, b1, a, 0, 0, 0);
        acc[c] = a;
      }
      unsigned short* trow = tmp5 + (size_t)r * N_U * 64;
#pragma unroll
      for (int i = 0; i < 4; ++i) {
        ushort4 o;
        o.x = f2bf(acc[0][i]); o.y = f2bf(acc[1][i]);
        o.z = f2bf(acc[2][i]); o.w = f2bf(acc[3][i]);
        *(ushort4*)(trow + (size_t)(r0 + q * 4 + i) * 64 + m * 4) = o;
      }
    }
  }
}

// ---------------------------------------------------------------------------
// MERGED sort + aggregate (proven R5/R10 form). One block per bucket,
// 512 threads, two-pass low-LDS sort; agg: 8 waves, wave handles every-8th
// node; 16-lane group g16 reads its group's key/val via broadcast ds_read,
// gathers the 128-B tmp5 row (ushort4/lane), register-FMA; 2-round
// shfl_xor(16,32) reduce; lane L writes column L.
// LDS: 16384+8192+512+516+512 = 25.6 KB -> wave-capped 4 blocks/CU.
// ---------------------------------------------------------------------------
__global__ __launch_bounds__(512, 8) void bucket_sort_agg(
    const unsigned* __restrict__ keyP, const unsigned short* __restrict__ valP,
    const unsigned* __restrict__ gcursor,
    const unsigned short* __restrict__ tmp5,
    const float* __restrict__ bias, float* __restrict__ out) {
  __shared__ unsigned okey[CAP];           // sorted+padded (max cnt+384 <= 3968)
  __shared__ unsigned short oval[CAP];
  __shared__ unsigned hist[128];
  __shared__ unsigned starts[129];
  __shared__ unsigned cur[128];
  int b = blockIdx.x;
  unsigned base = (unsigned)b * CAP;
  int cnt = (int)(gcursor[b] - base);
  if (cnt > CAPU) cnt = CAPU;   // ~7-sigma, statistically impossible
  for (int i = threadIdx.x; i < 128; i += 512) hist[i] = 0u;
  __syncthreads();
  for (int i = threadIdx.x; i < cnt; i += 512)
    atomicAdd(&hist[keyP[base + i] >> 19], 1u);
  __syncthreads();
  if (threadIdx.x == 0) {
    unsigned acc = 0u;
    for (int l = 0; l < 128; ++l) {
      starts[l] = acc;
      acc += (hist[l] + 3u) & ~3u;   // pad each node to multiple of 4
    }
    starts[128] = acc;
  }
  __syncthreads();
  unsigned tot = starts[128];
  for (int i = threadIdx.x; i < (int)tot; i += 512) { okey[i] = 0u; oval[i] = 0; }
  for (int l = threadIdx.x; l < 128; l += 512) cur[l] = starts[l];
  __syncthreads();
  for (int i = threadIdx.x; i < cnt; i += 512) {   // L2-hot re-read
    unsigned k = keyP[base + i];
    unsigned pos = atomicAdd(&cur[k >> 19], 1u);
    okey[pos] = k & 0x7FFFFu;
    oval[pos] = valP[base + i];
  }
  __syncthreads();

  // ---- aggregation from LDS ----
  int lane = threadIdx.x & 63;
  int wave = threadIdx.x >> 6;
  int g16 = lane >> 4;                      // entry subgroup 0..3
  int m = lane & 15;                        // column-slot group
  int nb0 = b * 128;
  int nodes = (N_U - nb0 < 128) ? (N_U - nb0) : 128;
  const unsigned short* tp = tmp5 + (m << 2);
  float bl = bias[lane];
  for (int l = wave; l < nodes; l += 8) {
    unsigned s = starts[l];
    unsigned e = starts[l + 1];
    float a0 = 0.f, a1 = 0.f, a2 = 0.f, a3 = 0.f;
    unsigned k = s;
    for (; k + 8 <= e; k += 8) {            // 2 gathers in flight
      unsigned key0 = okey[k + g16];
      unsigned key1 = okey[k + 4 + g16];
      float v0 = bf2f(oval[k + g16]);
      float v1 = bf2f(oval[k + 4 + g16]);
      ushort4 t0 = *(const ushort4*)(tp + (size_t)key0 * 64);
      ushort4 t1 = *(const ushort4*)(tp + (size_t)key1 * 64);
      a0 += v0 * bf2f(t0.x);
      a1 += v0 * bf2f(t0.y);
      a2 += v0 * bf2f(t0.z);
      a3 += v0 * bf2f(t0.w);
      a0 += v1 * bf2f(t1.x);
      a1 += v1 * bf2f(t1.y);
      a2 += v1 * bf2f(t1.z);
      a3 += v1 * bf2f(t1.w);
    }
    if (k < e) {                            // padded remainder: one group
      unsigned key0 = okey[k + g16];
      float v0 = bf2f(oval[k + g16]);
      ushort4 t0 = *(const ushort4*)(tp + (size_t)key0 * 64);
      a0 += v0 * bf2f(t0.x);
      a1 += v0 * bf2f(t0.y);
      a2 += v0 * bf2f(t0.z);
      a3 += v0 * bf2f(t0.w);
    }
    a0 += __shfl_xor(a0, 16); a0 += __shfl_xor(a0, 32);
    a1 += __shfl_xor(a1, 16); a1 += __shfl_xor(a1, 32);
    a2 += __shfl_xor(a2, 16); a2 += __shfl_xor(a2, 32);
    a3 += __shfl_xor(a3, 16); a3 += __shfl_xor(a3, 32);
    float r = (g16 & 2) ? ((g16 & 1) ? a3 : a2) : ((g16 & 1) ? a1 : a0);
    out[(size_t)(nb0 + l) * 64 + lane] = fmaxf(r + bl, 0.f);
  }
}

// ===========================================================================
// FALLBACK PATH (proven R4 atomic-scatter version, used if ws is small)
// ===========================================================================
__global__ __launch_bounds__(256) void gemm_kernel(
    const float* __restrict__ X, const unsigned short* __restrict__ bfrag,
    unsigned short* __restrict__ tmp) {
  int lane = threadIdx.x & 63;
  int wave = threadIdx.x >> 6;
  int q = lane >> 4, m = lane & 15;
  bf16x8 bf[8];
#pragma unroll
  for (int f = 0; f < 8; ++f)
    bf[f] = *(const bf16x8*)(bfrag + (f * 64 + lane) * 8);
  int t = blockIdx.x * 4 + wave;
  if (t >= N_U / 16) return;
  int r0 = t * 16;
  const float* xr = X + (size_t)(r0 + m) * 64;
  float4 p0 = *(const float4*)(xr + q * 8);
  float4 p1 = *(const float4*)(xr + q * 8 + 4);
  float4 p2 = *(const float4*)(xr + 32 + q * 8);
  float4 p3 = *(const float4*)(xr + 32 + q * 8 + 4);
  bf16x8 a0, a1;
  a0[0] = (short)f2bf(p0.x); a0[1] = (short)f2bf(p0.y);
  a0[2] = (short)f2bf(p0.z); a0[3] = (short)f2bf(p0.w);
  a0[4] = (short)f2bf(p1.x); a0[5] = (short)f2bf(p1.y);
  a0[6] = (short)f2bf(p1.z); a0[7] = (short)f2bf(p1.w);
  a1[0] = (short)f2bf(p2.x); a1[1] = (short)f2bf(p2.y);
  a1[2] = (short)f2bf(p2.z); a1[3] = (short)f2bf(p2.w);
  a1[4] = (short)f2bf(p3.x); a1[5] = (short)f2bf(p3.y);
  a1[6] = (short)f2bf(p3.z); a1[7] = (short)f2bf(p3.w);
#pragma unroll
  for (int c = 0; c < 4; ++c) {
    f32x4 acc = {0.f, 0.f, 0.f, 0.f};
    acc = __builtin_amdgcn_mfma_f32_16x16x32_bf16(a0, bf[c * 2 + 0], acc, 0, 0, 0);
    acc = __builtin_amdgcn_mfma_f32_16x16x32_bf16(a1, bf[c * 2 + 1], acc, 0, 0, 0);
#pragma unroll
    for (int i = 0; i < 4; ++i)
      tmp[(size_t)(r0 + q * 4 + i) * 64 + c * 16 + m] = f2bf(acc[i]);
  }
}

__global__ __launch_bounds__(256) void scatter_kernel(
    const unsigned short* __restrict__ tmp, const float* __restrict__ edge_val,
    const int* __restrict__ dst_idx, const int* __restrict__ src_idx,
    float* __restrict__ z, int base, int cnt) {
  int e = blockIdx.x * 4 + (threadIdx.x >> 6);
  int j = threadIdx.x & 63;
  int d = dst_idx[e] - base;
  if ((unsigned)d >= (unsigned)cnt) return;
  int s = src_idx[e];
  float w = edge_val[e];
  atomicAdd(&z[(size_t)d * 64 + j], w * bf2f(tmp[(size_t)s * 64 + j]));
}

__global__ __launch_bounds__(256) void finalize_kernel(
    const float* __restrict__ z, const float* __restrict__ bias,
    float* __restrict__ out) {
  size_t i4 = ((size_t)blockIdx.x * 256 + threadIdx.x) * 4;
  float4 zz = *(const float4*)(z + i4);
  const float4 bb = *(const float4*)(bias + (i4 & 63));
  float4 o;
  o.x = fmaxf(zz.x + bb.x, 0.f);
  o.y = fmaxf(zz.y + bb.y, 0.f);
  o.z = fmaxf(zz.z + bb.z, 0.f);
  o.w = fmaxf(zz.w + bb.w, 0.f);
  *(float4*)(out + i4) = o;
}

extern "C" void kernel_launch(void* const* d_in, const int* in_sizes, int n_in,
                              void* d_out, int out_size, void* d_ws, size_t ws_size,
                              hipStream_t stream) {
  const float* x_u      = (const float*)d_in[0];
  const float* x_v      = (const float*)d_in[1];
  const float* w_u      = (const float*)d_in[2];
  const float* w_v      = (const float*)d_in[3];
  const float* bias_u   = (const float*)d_in[4];
  const float* bias_v   = (const float*)d_in[5];
  const float* edge_val = (const float*)d_in[6];
  const int*   edge_u   = (const int*)d_in[7];
  const int*   edge_v   = (const int*)d_in[8];
  float* out = (float*)d_out;
  char* ws = (char*)d_ws;

  // Fast-path ws layout (83.8 MB <= proven 84.9 MB):
  //   bfrag    @ 0           131,072
  //   tmp5     @ 131,072     64,000,000                 -> 64,131,072
  //   gcur[2]  @ 64,131,072  2*4,096                    -> 64,139,264
  //   (unused) @ 64,139,264  405,504                    -> 64,544,768
  //   keyP0    @ 64,544,768  782*4096*4 = 12,812,288    -> 77,357,056
  //   valP0    @ 77,357,056  782*4096*2 =  6,406,144    -> 83,763,200
  // Side-1 key/val payload lives in OUT (dead scratch until sort_agg):
  //   keyP1 @ out+0 (12,812,288), valP1 @ out+12,812,288 (6,406,144)
  //   -> occupies [0, 19.2 MB) of out0's 25.6 MB half; consumed by
  //      sort_agg(side1) (writes only out1's half), then overwritten by
  //      sort_agg(side0).
  const size_t FAST_NEED = 83763200;

  unsigned short* bfrag = (unsigned short*)ws;

  if (ws_size >= FAST_NEED) {
    unsigned short* tmp5  = (unsigned short*)(ws + 131072);
    unsigned*       gcur  = (unsigned*)(ws + 64131072);   // [2][1024]
    unsigned*       keyP0 = (unsigned*)(ws + 64544768);
    unsigned short* valP0 = (unsigned short*)(ws + 77357056);
    unsigned*       keyP1 = (unsigned*)out;
    unsigned short* valP1 = (unsigned short*)((char*)out + 12812288);
    unsigned* gcur0 = gcur;
    unsigned* gcur1 = gcur + 1024;

    prep_weights<<<2, 256, 0, stream>>>(w_u, w_v, bfrag, gcur);

    // Step A: scatter side0 (dst=edge_u,src=edge_v -> keyP0) || scatter
    // side1 (dst=edge_v,src=edge_u -> keyP1 in out) || gemm side1
    // (tmp5 = x_u @ Wcum_u).  All independent.
    mega<<<SCAT_BLOCKS * 2 + GEMM_BLOCKS, 1024, 0, stream>>>(
        edge_u, edge_v, edge_v, edge_u, edge_val,
        gcur0, keyP0, valP0, gcur1, keyP1, valP1,
        x_u, bfrag /* Wcum_u */, tmp5, SCAT_BLOCKS, SCAT_BLOCKS);

    // Step B: side1 aggregate -> out1 (reads keyP1 in out0's half; writes
    // only out1's half -> disjoint).
    bucket_sort_agg<<<NB, 512, 0, stream>>>(keyP1, valP1, gcur1, tmp5,
                                            bias_v, out + (size_t)N_U * OO);

    // Step C: gemm side0 (tmp5 = x_v @ Wcum_v) — must follow B (B reads tmp5).
    mega<<<GEMM_BLOCKS, 1024, 0, stream>>>(
        edge_u, edge_v, edge_v, edge_u, edge_val,
        gcur0, keyP0, valP0, gcur1, keyP1, valP1,
        x_v, bfrag + RR * 4096 /* Wcum_v */, tmp5, 0, 0);

    // Step D: side0 aggregate -> out0 (keyP1 already consumed).
    bucket_sort_agg<<<NB, 512, 0, stream>>>(keyP0, valP0, gcur0, tmp5,
                                            bias_u, out);
    return;
  }

  // ---------------- Fallback: proven R4 path ----------------
  prep_weights<<<2, 256, 0, stream>>>(w_u, w_v, bfrag, (unsigned*)0);

  unsigned short* tmp = (unsigned short*)(ws + 131072);
  float*          z   = (float*)(ws + 131072 + 12800000);
  const size_t fixed = 131072 + 12800000;
  size_t zbytes = ws_size > fixed ? ws_size - fixed : 0;
  long chunk = (long)(zbytes / (OO * 4));
  chunk -= chunk % 16;
  if (chunk < 16) chunk = 16;
  if (chunk > N_U) chunk = N_U;

  const int gemm_grid = (N_U / 16 + 3) / 4;
  const int scat_grid = EE / 4;

  for (int side = 0; side < 2; ++side) {
    const float* X = side ? x_u : x_v;
    const unsigned short* frag0 = bfrag + (side ? 0 : RR * 4096);
    const int* dst = side ? edge_v : edge_u;
    const int* src = side ? edge_u : edge_v;
    const float* bias = side ? bias_v : bias_u;
    float* out_side = out + (size_t)side * N_U * OO;

    for (long base = 0; base < N_U; base += chunk) {
      long cnt = N_U - base < chunk ? N_U - base : chunk;
      hipMemsetAsync(z, 0, (size_t)cnt * OO * 4, stream);
      for (int r = 0; r < RR; ++r) {
        gemm_kernel<<<gemm_grid, 256, 0, stream>>>(X, frag0 + r * 4096, tmp);
        scatter_kernel<<<scat_grid, 256, 0, stream>>>(
            tmp, edge_val + (size_t)r * EE, dst + (size_t)r * EE,
            src + (size_t)r * EE, z, (int)base, (int)cnt);
      }
      finalize_kernel<<<(int)(cnt / 16), 256, 0, stream>>>(
          z, bias, out_side + base * OO);
    }
  }
}